// Round 2
// baseline (148.866 us; speedup 1.0000x reference)
//
#include <hip/hip_runtime.h>
#include <hip/hip_bf16.h>

typedef __bf16 bf16_t;
typedef __bf16 bf16x8 __attribute__((ext_vector_type(8)));
typedef float  f32x4  __attribute__((ext_vector_type(4)));

#define GLL16(gp, lp) __builtin_amdgcn_global_load_lds(                        \
    (const __attribute__((address_space(1))) unsigned int*)(gp),               \
    (__attribute__((address_space(3))) unsigned int*)(lp), 16, 0, 0)

#define BAR()    asm volatile("s_barrier" ::: "memory")
#define LGKM0()  asm volatile("s_waitcnt lgkmcnt(0)" ::: "memory")
#define VMCNT4() asm volatile("s_waitcnt vmcnt(4)" ::: "memory")

__device__ __forceinline__ float fast_sigmoid(float x) {
    return 1.f / (1.f + __expf(-x));
}
__device__ __forceinline__ float fast_tanh(float x) {
    float ax = fabsf(x);
    float t  = __expf(-2.f * ax);
    float r  = (1.f - t) / (1.f + t);
    return copysignf(r, x);
}

// ---------------- pack kernels: fp32 -> bf16 ----------------

// combined A[b][k] : k<512 from inputs, k>=512 from hidden. [16384][1024]
__global__ void pack_combined(const float* __restrict__ inp,
                              const float* __restrict__ hid,
                              bf16_t* __restrict__ A) {
    const size_t total = (size_t)16384 * 128;  // chunks of 8 elems
    size_t i = (size_t)blockIdx.x * blockDim.x + threadIdx.x;
    const size_t stride = (size_t)gridDim.x * blockDim.x;
    for (; i < total; i += stride) {
        size_t b = i >> 7;
        int kc = (int)(i & 127);
        const float* src = (kc < 64) ? (inp + b * 512 + kc * 8)
                                     : (hid + b * 512 + (kc - 64) * 8);
        float4 f0 = *(const float4*)src;
        float4 f1 = *(const float4*)(src + 4);
        bf16x8 v;
        v[0] = (bf16_t)f0.x; v[1] = (bf16_t)f0.y; v[2] = (bf16_t)f0.z; v[3] = (bf16_t)f0.w;
        v[4] = (bf16_t)f1.x; v[5] = (bf16_t)f1.y; v[6] = (bf16_t)f1.z; v[7] = (bf16_t)f1.w;
        *(bf16x8*)(A + i * 8) = v;
    }
}

// Gate-interleaved W pack: packed row n holds gate g=(n>>4)&3, j=(n>>6)*16+(n&15)
// so a 64-col MFMA wave strip = 16 j-values x 4 gates, and a thread's 4 n-frags
// (spaced 16) are the 4 gates of one j.
__global__ void pack_W(const float* __restrict__ wf, const float* __restrict__ wi,
                       const float* __restrict__ wo, const float* __restrict__ wc,
                       bf16_t* __restrict__ dst) {
    size_t idx = (size_t)blockIdx.x * blockDim.x + threadIdx.x;  // 262144 total
    int n  = (int)(idx >> 7);
    int ch = (int)(idx & 127);
    int g  = (n >> 4) & 3;
    int j  = ((n >> 6) << 4) | (n & 15);
    const float* src = (g == 0) ? wf : (g == 1) ? wi : (g == 2) ? wo : wc;
    src += (size_t)j * 1024 + ch * 8;
    float4 f0 = *(const float4*)src;
    float4 f1 = *(const float4*)(src + 4);
    bf16x8 v;
    v[0] = (bf16_t)f0.x; v[1] = (bf16_t)f0.y; v[2] = (bf16_t)f0.z; v[3] = (bf16_t)f0.w;
    v[4] = (bf16_t)f1.x; v[5] = (bf16_t)f1.y; v[6] = (bf16_t)f1.z; v[7] = (bf16_t)f1.w;
    *(bf16x8*)(dst + (size_t)n * 1024 + ch * 8) = v;
}

__global__ void cvt8(const float* __restrict__ src, bf16_t* __restrict__ dst, size_t n8) {
    size_t i = (size_t)blockIdx.x * blockDim.x + threadIdx.x;
    if (i >= n8) return;
    float4 f0 = ((const float4*)src)[i * 2];
    float4 f1 = ((const float4*)src)[i * 2 + 1];
    bf16x8 v;
    v[0] = (bf16_t)f0.x; v[1] = (bf16_t)f0.y; v[2] = (bf16_t)f0.z; v[3] = (bf16_t)f0.w;
    v[4] = (bf16_t)f1.x; v[5] = (bf16_t)f1.y; v[6] = (bf16_t)f1.z; v[7] = (bf16_t)f1.w;
    ((bf16x8*)dst)[i] = v;
}

// ---------------- 256x256x64 8-phase fused 4-gate GEMM ----------------
// gates[b][n] = sum_k A[b][k]*Wp[n][k];  M=16384, N=2048, K=1024.
// 8 waves (2M x 4N), per-wave 128x64 output, LDS 2x(32KB A + 32KB B) dbuf.
// Phase schedule per K-tile u (BK=64):
//   ph0: ds_read A(m0-3)+B(n0-1) | stage A-half0(u+1) | bar,lgkm0 | 16 MFMA | bar
//   ph1: ds_read B(n2-3)         | stage A-half1(u+1) | bar,lgkm0 | 16 MFMA | bar
//   ph2: ds_read A(m4-7)         | stage B-half0(u+2) | bar,lgkm0 | 16 MFMA | bar
//   ph3:                          | stage B-half1(u+2) | vmcnt(4),bar | 16 MFMA | bar
// vmcnt(4): after it, only B(u+2)'s 4 loads outstanding -> tile u+1 fully staged.
__global__ __launch_bounds__(512, 2) void gemm_gates(
        const bf16_t* __restrict__ A,     // [16384][1024]
        const bf16_t* __restrict__ Wp,    // [2048][1024] gate-interleaved
        const float* __restrict__ bF, const float* __restrict__ bI,
        const float* __restrict__ bO, const float* __restrict__ bC,
        const float* __restrict__ cell,   // [16384][512]
        float* __restrict__ out_cell,
        float* __restrict__ out_hid,
        bf16_t* __restrict__ hid_bf) {
    const int tid  = threadIdx.x;
    const int lane = tid & 63;
    const int wid  = tid >> 6;     // 0..7
    const int wm   = wid >> 2;     // 0..1 (M)
    const int wn   = wid & 3;      // 0..3 (N)
    const int bx   = blockIdx.x;   // 0..7  (N tiles)
    const int by   = blockIdx.y;   // 0..63 (M tiles)
    const int l15  = lane & 15;
    const int l16  = lane >> 4;

    __shared__ __align__(16) unsigned char sA[2][32768];  // [buf][256 rows][128 B]
    __shared__ __align__(16) unsigned char sB[2][32768];

    f32x4 acc[8][4];
#pragma unroll
    for (int m = 0; m < 8; ++m)
#pragma unroll
        for (int n = 0; n < 4; ++n) acc[m][n] = f32x4{0.f, 0.f, 0.f, 0.f};

    // staging: thread covers row (wid*8 + lane>>3) of each 64-row quarter (hq),
    // physical 16B slot lane&7 holds logical chunk (lane&7)^(lane>>3)  [XOR swizzle]
    const int srow = wid * 8 + (lane >> 3);
    const int schk = (lane & 7) ^ (lane >> 3);
    const bf16_t* a_base = A  + (size_t)(by * 256 + srow) * 1024 + schk * 8;
    const bf16_t* b_base = Wp + (size_t)(bx * 256 + srow) * 1024 + schk * 8;
    const unsigned ldsw = (unsigned)wid * 1024;

    auto stgA = [&](int su, int hq) {
        GLL16(a_base + (size_t)hq * 65536 + su * 64, &sA[su & 1][0] + hq * 8192 + ldsw);
    };
    auto stgB = [&](int su, int hq) {
        GLL16(b_base + (size_t)hq * 65536 + su * 64, &sB[su & 1][0] + hq * 8192 + ldsw);
    };
    // frag read with matching swizzle: row pitch 128B, slot = chunk ^ (row&7)
    auto rdA = [&](const unsigned char* base, int m, int kk) -> bf16x8 {
        int r = wm * 128 + m * 16 + l15;
        int s = (kk * 4 + l16) ^ (r & 7);
        return *reinterpret_cast<const bf16x8*>(base + r * 128 + s * 16);
    };
    auto rdB = [&](const unsigned char* base, int nf, int kk) -> bf16x8 {
        int r = wn * 64 + nf * 16 + l15;
        int s = (kk * 4 + l16) ^ (r & 7);
        return *reinterpret_cast<const bf16x8*>(base + r * 128 + s * 16);
    };

    // prologue: B(0) x4, A(0) x4, B(1) x4  -> vmcnt(4) retires tile 0 fully
#pragma unroll
    for (int hq = 0; hq < 4; ++hq) stgB(0, hq);
#pragma unroll
    for (int hq = 0; hq < 4; ++hq) stgA(0, hq);
#pragma unroll
    for (int hq = 0; hq < 4; ++hq) stgB(1, hq);
    VMCNT4();
    BAR();

    for (int u = 0; u < 16; ++u) {
        const unsigned char* aL = &sA[u & 1][0];
        const unsigned char* bL = &sB[u & 1][0];
        const int sa = (u + 1) & 15;
        const int sb = (u + 2) & 15;

        bf16x8 af[4][2], g01[2][2], g23[2][2];

        // ---- phase 0: A m0-3 + B n0-1 (12 ds_reads), stage A-half0(u+1)
#pragma unroll
        for (int m = 0; m < 4; ++m) { af[m][0] = rdA(aL, m, 0); af[m][1] = rdA(aL, m, 1); }
#pragma unroll
        for (int n = 0; n < 2; ++n) { g01[n][0] = rdB(bL, n, 0); g01[n][1] = rdB(bL, n, 1); }
        stgA(sa, 0); stgA(sa, 1);
        BAR(); LGKM0();
        __builtin_amdgcn_s_setprio(1);
#pragma unroll
        for (int m = 0; m < 4; ++m)
#pragma unroll
            for (int n = 0; n < 2; ++n) {
                acc[m][n] = __builtin_amdgcn_mfma_f32_16x16x32_bf16(af[m][0], g01[n][0], acc[m][n], 0, 0, 0);
                acc[m][n] = __builtin_amdgcn_mfma_f32_16x16x32_bf16(af[m][1], g01[n][1], acc[m][n], 0, 0, 0);
            }
        __builtin_amdgcn_s_setprio(0);
        BAR();

        // ---- phase 1: B n2-3 (4 ds_reads), stage A-half1(u+1)
#pragma unroll
        for (int n = 0; n < 2; ++n) { g23[n][0] = rdB(bL, 2 + n, 0); g23[n][1] = rdB(bL, 2 + n, 1); }
        stgA(sa, 2); stgA(sa, 3);
        BAR(); LGKM0();
        __builtin_amdgcn_s_setprio(1);
#pragma unroll
        for (int m = 0; m < 4; ++m)
#pragma unroll
            for (int n = 0; n < 2; ++n) {
                acc[m][2 + n] = __builtin_amdgcn_mfma_f32_16x16x32_bf16(af[m][0], g23[n][0], acc[m][2 + n], 0, 0, 0);
                acc[m][2 + n] = __builtin_amdgcn_mfma_f32_16x16x32_bf16(af[m][1], g23[n][1], acc[m][2 + n], 0, 0, 0);
            }
        __builtin_amdgcn_s_setprio(0);
        BAR();

        // ---- phase 2: A m4-7 (8 ds_reads), stage B-half0(u+2)
#pragma unroll
        for (int m = 0; m < 4; ++m) { af[m][0] = rdA(aL, 4 + m, 0); af[m][1] = rdA(aL, 4 + m, 1); }
        stgB(sb, 0); stgB(sb, 1);
        BAR(); LGKM0();
        __builtin_amdgcn_s_setprio(1);
#pragma unroll
        for (int m = 0; m < 4; ++m)
#pragma unroll
            for (int n = 0; n < 2; ++n) {
                acc[4 + m][n] = __builtin_amdgcn_mfma_f32_16x16x32_bf16(af[m][0], g01[n][0], acc[4 + m][n], 0, 0, 0);
                acc[4 + m][n] = __builtin_amdgcn_mfma_f32_16x16x32_bf16(af[m][1], g01[n][1], acc[4 + m][n], 0, 0, 0);
            }
        __builtin_amdgcn_s_setprio(0);
        BAR();

        // ---- phase 3: no ds_reads, stage B-half1(u+2), counted vmcnt
        stgB(sb, 2); stgB(sb, 3);
        VMCNT4();
        BAR();
        __builtin_amdgcn_s_setprio(1);
#pragma unroll
        for (int m = 0; m < 4; ++m)
#pragma unroll
            for (int n = 0; n < 2; ++n) {
                acc[4 + m][2 + n] = __builtin_amdgcn_mfma_f32_16x16x32_bf16(af[m][0], g23[n][0], acc[4 + m][2 + n], 0, 0, 0);
                acc[4 + m][2 + n] = __builtin_amdgcn_mfma_f32_16x16x32_bf16(af[m][1], g23[n][1], acc[4 + m][2 + n], 0, 0, 0);
            }
        __builtin_amdgcn_s_setprio(0);
        BAR();
    }

    // ---- fused LSTM epilogue. Thread's n-frag index IS the gate (g=nf),
    // j = (bx*4+wn)*16 + (lane&15) for all frags.
    const int jj = (bx * 4 + wn) * 16 + l15;
    const float bf_ = bF[jj], bi_ = bI[jj], bo_ = bO[jj], bc_ = bC[jj];
    const int rbase = by * 256 + wm * 128 + l16 * 4;
#pragma unroll
    for (int m = 0; m < 8; ++m) {
#pragma unroll
        for (int e = 0; e < 4; ++e) {
            int row = rbase + m * 16 + e;
            size_t idx = (size_t)row * 512 + jj;
            float fg = fast_sigmoid(acc[m][0][e] + bf_);
            float ig = fast_sigmoid(acc[m][1][e] + bi_);
            float og = fast_sigmoid(acc[m][2][e] + bo_);
            float cg = fast_tanh(acc[m][3][e] + bc_);
            float cs = cell[idx];
            float nc = fg * cs + ig * cg;
            float nh = og * fast_tanh(nc);
            out_cell[idx] = nc;
            out_hid[idx]  = nh;
            hid_bf[idx]   = (bf16_t)nh;
        }
    }
}

// ---------------- output GEMM: out = hid @ V^T + vb (round-1 verified) ----------------
__global__ void gemm_out(const bf16_t* __restrict__ Ah,   // [16384][512]
                         const bf16_t* __restrict__ V,    // [512][512] (row n, col k)
                         const float* __restrict__ vb,
                         float* __restrict__ out) {
    constexpr int K = 512;
    const int tid  = threadIdx.x;
    const int lane = tid & 63;
    const int wid  = tid >> 6;
    const int wm   = wid >> 1;
    const int wn   = wid & 1;
    const int mtile = blockIdx.y * 128;
    const int ntile = blockIdx.x * 128;

    __shared__ __align__(16) unsigned char sA[128 * 64];
    __shared__ __align__(16) unsigned char sB[128 * 64];

    f32x4 acc[4][4];  // [n-frag][m-frag]
#pragma unroll
    for (int n = 0; n < 4; ++n)
#pragma unroll
        for (int m = 0; m < 4; ++m) acc[n][m] = f32x4{0.f, 0.f, 0.f, 0.f};

    const bf16_t* gA[2]; const bf16_t* gB[2];
    unsigned ldsOff[2];
#pragma unroll
    for (int q = 0; q < 2; ++q) {
        int ch = q * 4 + wid;
        int r  = ch * 16 + (lane >> 2);
        int cphys = lane & 3;
        int clog  = cphys ^ ((r >> 1) & 3);
        gA[q] = Ah + (size_t)(mtile + r) * K + clog * 8;
        gB[q] = V  + (size_t)(ntile + r) * K + clog * 8;
        ldsOff[q] = (unsigned)ch * 1024;
    }

    for (int k0 = 0; k0 < K; k0 += 32) {
#pragma unroll
        for (int q = 0; q < 2; ++q) {
            GLL16(gA[q] + k0, sA + ldsOff[q]);
            GLL16(gB[q] + k0, sB + ldsOff[q]);
        }
        __syncthreads();

        bf16x8 af[4], bfv[4];
#pragma unroll
        for (int m = 0; m < 4; ++m) {
            int r = wm * 64 + m * 16 + (lane & 15);
            int c = (lane >> 4) ^ ((r >> 1) & 3);
            af[m] = *reinterpret_cast<const bf16x8*>(sA + r * 64 + c * 16);
        }
#pragma unroll
        for (int n = 0; n < 4; ++n) {
            int r = wn * 64 + n * 16 + (lane & 15);
            int c = (lane >> 4) ^ ((r >> 1) & 3);
            bfv[n] = *reinterpret_cast<const bf16x8*>(sB + r * 64 + c * 16);
        }
#pragma unroll
        for (int n = 0; n < 4; ++n)
#pragma unroll
            for (int m = 0; m < 4; ++m)
                acc[n][m] = __builtin_amdgcn_mfma_f32_16x16x32_bf16(af[m], bfv[n], acc[n][m], 0, 0, 0);
        __syncthreads();
    }

    const int cl = lane & 15;
#pragma unroll
    for (int n = 0; n < 4; ++n) {
        int coln = ntile + wn * 64 + n * 16 + cl;
        float b = vb[coln];
#pragma unroll
        for (int m = 0; m < 4; ++m) {
#pragma unroll
            for (int e = 0; e < 4; ++e) {
                int row = mtile + wm * 64 + m * 16 + (lane >> 4) * 4 + e;
                out[(size_t)row * 512 + coln] = acc[n][m][e] + b;
            }
        }
    }
}

extern "C" void kernel_launch(void* const* d_in, const int* in_sizes, int n_in,
                              void* d_out, int out_size, void* d_ws, size_t ws_size,
                              hipStream_t stream) {
    const float* inputs = (const float*)d_in[0];
    const float* cell   = (const float*)d_in[1];
    const float* hidden = (const float*)d_in[2];
    const float* Wf_w = (const float*)d_in[3];
    const float* Wf_b = (const float*)d_in[4];
    const float* Wi_w = (const float*)d_in[5];
    const float* Wi_b = (const float*)d_in[6];
    const float* Wc_w = (const float*)d_in[7];
    const float* Wc_b = (const float*)d_in[8];
    const float* Wo_w = (const float*)d_in[9];
    const float* Wo_b = (const float*)d_in[10];
    const float* V_w  = (const float*)d_in[11];
    const float* V_b  = (const float*)d_in[12];
    float* out = (float*)d_out;

    char* ws = (char*)d_ws;
    bf16_t* A_bf = (bf16_t*)(ws);                                  // 32 MB
    bf16_t* W_bf = (bf16_t*)(ws + 33554432);                       // 4 MB
    bf16_t* V_bf = (bf16_t*)(ws + 33554432 + 4194304);             // 0.5 MB
    bf16_t* h_bf = (bf16_t*)(ws + 33554432 + 4194304 + 524288);    // 16 MB

    pack_combined<<<2048, 256, 0, stream>>>(inputs, hidden, A_bf);
    pack_W<<<1024, 256, 0, stream>>>(Wf_w, Wi_w, Wo_w, Wc_w, W_bf);
    cvt8<<<128, 256, 0, stream>>>(V_w, V_bf, 32768);

    // 256x256 8-phase gate GEMM + fused LSTM elementwise
    gemm_gates<<<dim3(8, 64), 512, 0, stream>>>(
        A_bf, W_bf, Wf_b, Wi_b, Wo_b, Wc_b, cell,
        out, out + (size_t)16384 * 512, h_bf);

    // output GEMM
    gemm_out<<<dim3(4, 128), 256, 0, stream>>>(
        h_bf, V_bf, V_b, out + (size_t)2 * 16384 * 512);
}

// Round 3
// 128.779 us; speedup vs baseline: 1.1560x; 1.1560x over previous
//
#include <hip/hip_runtime.h>
#include <hip/hip_bf16.h>

typedef __bf16 bf16_t;
typedef __bf16 bf16x8 __attribute__((ext_vector_type(8)));
typedef float  f32x4  __attribute__((ext_vector_type(4)));

#define GLL16(gp, lp) __builtin_amdgcn_global_load_lds(                        \
    (const __attribute__((address_space(1))) unsigned int*)(gp),               \
    (__attribute__((address_space(3))) unsigned int*)(lp), 16, 0, 0)

#define BAR()    asm volatile("s_barrier" ::: "memory")
#define VMCNT4() asm volatile("s_waitcnt vmcnt(4)" ::: "memory")
#define VMCNT2() asm volatile("s_waitcnt vmcnt(2)" ::: "memory")
#define VMCNT0() asm volatile("s_waitcnt vmcnt(0)" ::: "memory")

__device__ __forceinline__ float fast_sigmoid(float x) {
    return 1.f / (1.f + __expf(-x));
}
__device__ __forceinline__ float fast_tanh(float x) {
    float ax = fabsf(x);
    float t  = __expf(-2.f * ax);
    float r  = (1.f - t) / (1.f + t);
    return copysignf(r, x);
}

// ---------------- pack kernels: fp32 -> bf16 ----------------

__global__ void pack_combined(const float* __restrict__ inp,
                              const float* __restrict__ hid,
                              bf16_t* __restrict__ A) {
    const size_t total = (size_t)16384 * 128;
    size_t i = (size_t)blockIdx.x * blockDim.x + threadIdx.x;
    const size_t stride = (size_t)gridDim.x * blockDim.x;
    for (; i < total; i += stride) {
        size_t b = i >> 7;
        int kc = (int)(i & 127);
        const float* src = (kc < 64) ? (inp + b * 512 + kc * 8)
                                     : (hid + b * 512 + (kc - 64) * 8);
        float4 f0 = *(const float4*)src;
        float4 f1 = *(const float4*)(src + 4);
        bf16x8 v;
        v[0] = (bf16_t)f0.x; v[1] = (bf16_t)f0.y; v[2] = (bf16_t)f0.z; v[3] = (bf16_t)f0.w;
        v[4] = (bf16_t)f1.x; v[5] = (bf16_t)f1.y; v[6] = (bf16_t)f1.z; v[7] = (bf16_t)f1.w;
        *(bf16x8*)(A + i * 8) = v;
    }
}

// Gate-interleaved W pack: packed row n holds gate g=(n>>4)&3, j=(n>>6)*16+(n&15)
__global__ void pack_W(const float* __restrict__ wf, const float* __restrict__ wi,
                       const float* __restrict__ wo, const float* __restrict__ wc,
                       bf16_t* __restrict__ dst) {
    size_t idx = (size_t)blockIdx.x * blockDim.x + threadIdx.x;  // 262144 total
    int n  = (int)(idx >> 7);
    int ch = (int)(idx & 127);
    int g  = (n >> 4) & 3;
    int j  = ((n >> 6) << 4) | (n & 15);
    const float* src = (g == 0) ? wf : (g == 1) ? wi : (g == 2) ? wo : wc;
    src += (size_t)j * 1024 + ch * 8;
    float4 f0 = *(const float4*)src;
    float4 f1 = *(const float4*)(src + 4);
    bf16x8 v;
    v[0] = (bf16_t)f0.x; v[1] = (bf16_t)f0.y; v[2] = (bf16_t)f0.z; v[3] = (bf16_t)f0.w;
    v[4] = (bf16_t)f1.x; v[5] = (bf16_t)f1.y; v[6] = (bf16_t)f1.z; v[7] = (bf16_t)f1.w;
    *(bf16x8*)(dst + (size_t)n * 1024 + ch * 8) = v;
}

__global__ void cvt8(const float* __restrict__ src, bf16_t* __restrict__ dst, size_t n8) {
    size_t i = (size_t)blockIdx.x * blockDim.x + threadIdx.x;
    if (i >= n8) return;
    float4 f0 = ((const float4*)src)[i * 2];
    float4 f1 = ((const float4*)src)[i * 2 + 1];
    bf16x8 v;
    v[0] = (bf16_t)f0.x; v[1] = (bf16_t)f0.y; v[2] = (bf16_t)f0.z; v[3] = (bf16_t)f0.w;
    v[4] = (bf16_t)f1.x; v[5] = (bf16_t)f1.y; v[6] = (bf16_t)f1.z; v[7] = (bf16_t)f1.w;
    ((bf16x8*)dst)[i] = v;
}

// ---------------- 256x256x64 4-phase fused 4-gate GEMM ----------------
// Staging: tile u+1 (A and B) -> buf[(u+1)&1], 2 GLL/phase, quarters:
//   ph0: B q0,q1 | ph1: B q2,q3, vmcnt(4) | ph2: A q0,q2 | ph3: A q1,q3, vmcnt(2)
// vmcnt ledger (per-thread outstanding GLLs):
//   at ph1 wait: A(u)q1,q3 (old,2) + B(u+1) (4) = 6 -> vmcnt(4) retires A(u)q1,q3
//     (needed by THIS iter's ph2 reads; ~2 phases of cover)
//   at ph3 wait: B(u+1)4 + A(u+1)q0,q2 + A(u+1)q1,q3 = 8 -> vmcnt(2) retires
//     B(u+1)+A(u+1)q0,q2 (needed by next iter ph0), leaves A(u+1)q1,q3 in flight.
// No explicit lgkmcnt: ds_reads are compiler-visible; compiler emits per-dep
// counted lgkmcnt so tail reads drain under the early MFMAs of each phase.
__global__ __launch_bounds__(512, 2) void gemm_gates(
        const bf16_t* __restrict__ A,     // [16384][1024]
        const bf16_t* __restrict__ Wp,    // [2048][1024] gate-interleaved
        const float* __restrict__ bF, const float* __restrict__ bI,
        const float* __restrict__ bO, const float* __restrict__ bC,
        const float* __restrict__ cell,   // [16384][512]
        float* __restrict__ out_cell,
        float* __restrict__ out_hid,
        bf16_t* __restrict__ hid_bf) {
    const int tid  = threadIdx.x;
    const int lane = tid & 63;
    const int wid  = tid >> 6;     // 0..7
    const int wm   = wid >> 2;     // 0..1 (M)
    const int wn   = wid & 3;      // 0..3 (N)
    const int l15  = lane & 15;
    const int l16  = lane >> 4;

    // XCD-contiguous swizzle (T1): hw id w (x-fastest, 512 wgs, 8 XCDs,
    // round-robin) -> serviced tile s so XCD x runs s in [x*64, x*64+64):
    // by-range of 8 contiguous M-panels per XCD => 8x in-L2 A reuse.
    const int w  = blockIdx.y * 8 + blockIdx.x;
    const int s  = (w & 7) * 64 + (w >> 3);
    const int by = s >> 3;   // 0..63
    const int bx = s & 7;    // 0..7

    __shared__ __align__(16) unsigned char sA[2][32768];  // [buf][256 rows][128 B]
    __shared__ __align__(16) unsigned char sB[2][32768];

    f32x4 acc[8][4];
#pragma unroll
    for (int m = 0; m < 8; ++m)
#pragma unroll
        for (int n = 0; n < 4; ++n) acc[m][n] = f32x4{0.f, 0.f, 0.f, 0.f};

    // staging: thread covers row (wid*8 + lane>>3) of each 64-row quarter,
    // physical 16B slot lane&7 holds logical chunk (lane&7)^(lane>>3)
    const int srow = wid * 8 + (lane >> 3);
    const int schk = (lane & 7) ^ (lane >> 3);
    const bf16_t* a_base = A  + (size_t)(by * 256 + srow) * 1024 + schk * 8;
    const bf16_t* b_base = Wp + (size_t)(bx * 256 + srow) * 1024 + schk * 8;
    const unsigned ldsw = (unsigned)wid * 1024;

    auto stgA = [&](int d, int koff, int q) {
        GLL16(a_base + (size_t)q * 65536 + koff * 64, &sA[d][0] + q * 8192 + ldsw);
    };
    auto stgB = [&](int d, int koff, int q) {
        GLL16(b_base + (size_t)q * 65536 + koff * 64, &sB[d][0] + q * 8192 + ldsw);
    };
    auto rdA = [&](const unsigned char* base, int m, int kk) -> bf16x8 {
        int r = wm * 128 + m * 16 + l15;
        int sl = (kk * 4 + l16) ^ (r & 7);
        return *reinterpret_cast<const bf16x8*>(base + r * 128 + sl * 16);
    };
    auto rdB = [&](const unsigned char* base, int nf, int kk) -> bf16x8 {
        int r = wn * 64 + nf * 16 + l15;
        int sl = (kk * 4 + l16) ^ (r & 7);
        return *reinterpret_cast<const bf16x8*>(base + r * 128 + sl * 16);
    };

    // prologue: tile 0 fully (B then A), full drain
#pragma unroll
    for (int q = 0; q < 4; ++q) stgB(0, 0, q);
#pragma unroll
    for (int q = 0; q < 4; ++q) stgA(0, 0, q);
    VMCNT0();
    BAR();

    for (int u = 0; u < 16; ++u) {
        const unsigned char* aL = &sA[u & 1][0];
        const unsigned char* bL = &sB[u & 1][0];
        const int d    = (u + 1) & 1;
        const int koff = (u < 15) ? (u + 1) : 15;  // clamp: tail stages are unused

        bf16x8 af[4][2], g01[2][2], g23[2][2];

        // ---- phase 0: reads A m0-3 (8) + B n0-1 (4); stage B(u+1) q0,q1
#pragma unroll
        for (int m = 0; m < 4; ++m) { af[m][0] = rdA(aL, m, 0); af[m][1] = rdA(aL, m, 1); }
#pragma unroll
        for (int n = 0; n < 2; ++n) { g01[n][0] = rdB(bL, n, 0); g01[n][1] = rdB(bL, n, 1); }
        stgB(d, koff, 0); stgB(d, koff, 1);
        BAR();
        __builtin_amdgcn_s_setprio(1);
#pragma unroll
        for (int m = 0; m < 4; ++m)
#pragma unroll
            for (int n = 0; n < 2; ++n) {
                acc[m][n] = __builtin_amdgcn_mfma_f32_16x16x32_bf16(af[m][0], g01[n][0], acc[m][n], 0, 0, 0);
                acc[m][n] = __builtin_amdgcn_mfma_f32_16x16x32_bf16(af[m][1], g01[n][1], acc[m][n], 0, 0, 0);
            }
        __builtin_amdgcn_s_setprio(0);
        BAR();

        // ---- phase 1: reads B n2-3 (4); stage B(u+1) q2,q3; vmcnt(4)
#pragma unroll
        for (int n = 0; n < 2; ++n) { g23[n][0] = rdB(bL, 2 + n, 0); g23[n][1] = rdB(bL, 2 + n, 1); }
        stgB(d, koff, 2); stgB(d, koff, 3);
        BAR();
        __builtin_amdgcn_s_setprio(1);
#pragma unroll
        for (int m = 0; m < 4; ++m)
#pragma unroll
            for (int n = 0; n < 2; ++n) {
                acc[m][2 + n] = __builtin_amdgcn_mfma_f32_16x16x32_bf16(af[m][0], g23[n][0], acc[m][2 + n], 0, 0, 0);
                acc[m][2 + n] = __builtin_amdgcn_mfma_f32_16x16x32_bf16(af[m][1], g23[n][1], acc[m][2 + n], 0, 0, 0);
            }
        __builtin_amdgcn_s_setprio(0);
        VMCNT4();   // retires A(u) q1,q3 -> safe for ph2 reads after barrier
        BAR();

        // ---- phase 2: reads A m4-7 (8); stage A(u+1) q0,q2
#pragma unroll
        for (int m = 0; m < 4; ++m) { af[m][0] = rdA(aL, 4 + m, 0); af[m][1] = rdA(aL, 4 + m, 1); }
        stgA(d, koff, 0); stgA(d, koff, 2);
        BAR();
        __builtin_amdgcn_s_setprio(1);
#pragma unroll
        for (int m = 0; m < 4; ++m)
#pragma unroll
            for (int n = 0; n < 2; ++n) {
                acc[4 + m][n] = __builtin_amdgcn_mfma_f32_16x16x32_bf16(af[m][0], g01[n][0], acc[4 + m][n], 0, 0, 0);
                acc[4 + m][n] = __builtin_amdgcn_mfma_f32_16x16x32_bf16(af[m][1], g01[n][1], acc[4 + m][n], 0, 0, 0);
            }
        __builtin_amdgcn_s_setprio(0);
        BAR();

        // ---- phase 3: no reads; stage A(u+1) q1,q3; vmcnt(2)
        stgA(d, koff, 1); stgA(d, koff, 3);
        BAR();
        __builtin_amdgcn_s_setprio(1);
#pragma unroll
        for (int m = 0; m < 4; ++m)
#pragma unroll
            for (int n = 0; n < 2; ++n) {
                acc[4 + m][2 + n] = __builtin_amdgcn_mfma_f32_16x16x32_bf16(af[m][0], g23[n][0], acc[4 + m][2 + n], 0, 0, 0);
                acc[4 + m][2 + n] = __builtin_amdgcn_mfma_f32_16x16x32_bf16(af[m][1], g23[n][1], acc[4 + m][2 + n], 0, 0, 0);
            }
        __builtin_amdgcn_s_setprio(0);
        VMCNT2();   // retires B(u+1) + A(u+1) q0,q2 -> safe for next ph0
        BAR();
    }

    // ---- fused LSTM epilogue; n-frag index IS the gate, j = (bx*4+wn)*16+l15
    const int jj = (bx * 4 + wn) * 16 + l15;
    const float bf_ = bF[jj], bi_ = bI[jj], bo_ = bO[jj], bc_ = bC[jj];
    const int rbase = by * 256 + wm * 128 + l16 * 4;
#pragma unroll
    for (int m = 0; m < 8; ++m) {
#pragma unroll
        for (int e = 0; e < 4; ++e) {
            int row = rbase + m * 16 + e;
            size_t idx = (size_t)row * 512 + jj;
            float fg = fast_sigmoid(acc[m][0][e] + bf_);
            float ig = fast_sigmoid(acc[m][1][e] + bi_);
            float og = fast_sigmoid(acc[m][2][e] + bo_);
            float cg = fast_tanh(acc[m][3][e] + bc_);
            float cs = cell[idx];
            float nc = fg * cs + ig * cg;
            float nh = og * fast_tanh(nc);
            out_cell[idx] = nc;
            out_hid[idx]  = nh;
            hid_bf[idx]   = (bf16_t)nh;
        }
    }
}

// ---------------- output GEMM: out = hid @ V^T + vb ----------------
__global__ void gemm_out(const bf16_t* __restrict__ Ah,   // [16384][512]
                         const bf16_t* __restrict__ V,    // [512][512]
                         const float* __restrict__ vb,
                         float* __restrict__ out) {
    constexpr int K = 512;
    const int tid  = threadIdx.x;
    const int lane = tid & 63;
    const int wid  = tid >> 6;
    const int wm   = wid >> 1;
    const int wn   = wid & 1;
    // XCD-contiguous swizzle: 512 wgs, chunk 64
    const int w  = blockIdx.y * 4 + blockIdx.x;
    const int s  = (w & 7) * 64 + (w >> 3);
    const int mtile = (s >> 2) * 128;
    const int ntile = (s & 3) * 128;

    __shared__ __align__(16) unsigned char sA[128 * 64];
    __shared__ __align__(16) unsigned char sB[128 * 64];

    f32x4 acc[4][4];
#pragma unroll
    for (int n = 0; n < 4; ++n)
#pragma unroll
        for (int m = 0; m < 4; ++m) acc[n][m] = f32x4{0.f, 0.f, 0.f, 0.f};

    const bf16_t* gA[2]; const bf16_t* gB[2];
    unsigned ldsOff[2];
#pragma unroll
    for (int q = 0; q < 2; ++q) {
        int ch = q * 4 + wid;
        int r  = ch * 16 + (lane >> 2);
        int cphys = lane & 3;
        int clog  = cphys ^ ((r >> 1) & 3);
        gA[q] = Ah + (size_t)(mtile + r) * K + clog * 8;
        gB[q] = V  + (size_t)(ntile + r) * K + clog * 8;
        ldsOff[q] = (unsigned)ch * 1024;
    }

    for (int k0 = 0; k0 < K; k0 += 32) {
#pragma unroll
        for (int q = 0; q < 2; ++q) {
            GLL16(gA[q] + k0, sA + ldsOff[q]);
            GLL16(gB[q] + k0, sB + ldsOff[q]);
        }
        __syncthreads();

        bf16x8 af[4], bfv[4];
#pragma unroll
        for (int m = 0; m < 4; ++m) {
            int r = wm * 64 + m * 16 + (lane & 15);
            int c = (lane >> 4) ^ ((r >> 1) & 3);
            af[m] = *reinterpret_cast<const bf16x8*>(sA + r * 64 + c * 16);
        }
#pragma unroll
        for (int n = 0; n < 4; ++n) {
            int r = wn * 64 + n * 16 + (lane & 15);
            int c = (lane >> 4) ^ ((r >> 1) & 3);
            bfv[n] = *reinterpret_cast<const bf16x8*>(sB + r * 64 + c * 16);
        }
#pragma unroll
        for (int n = 0; n < 4; ++n)
#pragma unroll
            for (int m = 0; m < 4; ++m)
                acc[n][m] = __builtin_amdgcn_mfma_f32_16x16x32_bf16(af[m], bfv[n], acc[n][m], 0, 0, 0);
        __syncthreads();
    }

    const int cl = lane & 15;
#pragma unroll
    for (int n = 0; n < 4; ++n) {
        int coln = ntile + wn * 64 + n * 16 + cl;
        float b = vb[coln];
#pragma unroll
        for (int m = 0; m < 4; ++m) {
#pragma unroll
            for (int e = 0; e < 4; ++e) {
                int row = mtile + wm * 64 + m * 16 + (lane >> 4) * 4 + e;
                out[(size_t)row * 512 + coln] = acc[n][m][e] + b;
            }
        }
    }
}

extern "C" void kernel_launch(void* const* d_in, const int* in_sizes, int n_in,
                              void* d_out, int out_size, void* d_ws, size_t ws_size,
                              hipStream_t stream) {
    const float* inputs = (const float*)d_in[0];
    const float* cell   = (const float*)d_in[1];
    const float* hidden = (const float*)d_in[2];
    const float* Wf_w = (const float*)d_in[3];
    const float* Wf_b = (const float*)d_in[4];
    const float* Wi_w = (const float*)d_in[5];
    const float* Wi_b = (const float*)d_in[6];
    const float* Wc_w = (const float*)d_in[7];
    const float* Wc_b = (const float*)d_in[8];
    const float* Wo_w = (const float*)d_in[9];
    const float* Wo_b = (const float*)d_in[10];
    const float* V_w  = (const float*)d_in[11];
    const float* V_b  = (const float*)d_in[12];
    float* out = (float*)d_out;

    char* ws = (char*)d_ws;
    bf16_t* A_bf = (bf16_t*)(ws);                                  // 32 MB
    bf16_t* W_bf = (bf16_t*)(ws + 33554432);                       // 4 MB
    bf16_t* V_bf = (bf16_t*)(ws + 33554432 + 4194304);             // 0.5 MB
    bf16_t* h_bf = (bf16_t*)(ws + 33554432 + 4194304 + 524288);    // 16 MB

    pack_combined<<<2048, 256, 0, stream>>>(inputs, hidden, A_bf);
    pack_W<<<1024, 256, 0, stream>>>(Wf_w, Wi_w, Wo_w, Wc_w, W_bf);
    cvt8<<<128, 256, 0, stream>>>(V_w, V_bf, 32768);

    gemm_gates<<<dim3(8, 64), 512, 0, stream>>>(
        A_bf, W_bf, Wf_b, Wi_b, Wo_b, Wc_b, cell,
        out, out + (size_t)16384 * 512, h_bf);

    gemm_out<<<dim3(4, 128), 256, 0, stream>>>(
        h_bf, V_bf, V_b, out + (size_t)2 * 16384 * 512);
}